// Round 3
// baseline (233.220 us; speedup 1.0000x reference)
//
#include <hip/hip_runtime.h>
#include <stdint.h>

typedef unsigned long long u64;

#define NCAND   4096
#define M2      8192            // 2N
#define NWORDS  128             // M2/64
#define SCORE_T 0.5f
#define IOU_T   0.5f
#define JSPLIT  8               // j-range splits for the counting sort

// ---------------- workspace layout (bytes) ----------------
// hdr[0] = V (atomicMax in k_scatter; 0xAA poison is negative -> no init needed)
// hdr[1] = maxcoord f32 bits (atomicMax in k_build; poison negative -> safe)
// hdr[2] = progress counter for chained NMS (publishers store absolute W+1 -> no init)
#define OFF_HDR     0
#define OFF_KEEP    64                         // u64[128] final keep bitmask
#define OFF_KEYS    4096                       // u64[8192]
#define OFF_PART    (OFF_KEYS + 65536)         // int[JSPLIT][8192]
#define OFF_OAREA   (OFF_PART + JSPLIT*32768)  // float[8192]
#define OFF_SSCORE  (OFF_OAREA + 32768)        // float[8192] sorted original scores
#define OFF_SLABEL  (OFF_SSCORE + 32768)       // int[8192]   sorted labels
#define OFF_SB      (OFF_SLABEL + 32768)       // float4[8192] sorted boxes
#define OFF_OBOX    (OFF_SB + 131072)          // float4[8192] sorted offset boxes
#define OFF_MASK    (OFF_OBOX + 131072)        // u64 mask_T[128][8192]  (TRANSPOSED: word-major)
// total ≈ 9.1 MiB

__device__ __forceinline__ unsigned order_key(float f) {
    unsigned u = __float_as_uint(f);
    return (u & 0x80000000u) ? ~u : (u | 0x80000000u);  // ascending uint == ascending float
}

__device__ __forceinline__ float get_width(const int* widthp) {
    int wi = widthp[0];
    return (wi > 0 && wi < 1000000) ? (float)wi : __int_as_float(wi);
}

// Recompute the combined (flip-adjusted) candidate `idx` straight from inputs.
__device__ __forceinline__ void fetch_cand(int idx, const float* b1, const float* b2,
                                           const float* s1, const float* s2,
                                           const int* l1, const int* l2, float wf,
                                           float& x1, float& y1, float& x2, float& y2,
                                           float& sc, int& lb) {
#pragma clang fp contract(off)
    if (idx < NCAND) {
        x1 = b1[idx*4+0]; y1 = b1[idx*4+1]; x2 = b1[idx*4+2]; y2 = b1[idx*4+3];
        sc = s1[idx]; lb = l1[idx];
    } else {
        int m = idx - NCAND;
        float bx1 = b2[m*4+0], by1 = b2[m*4+1], bx2 = b2[m*4+2], by2 = b2[m*4+3];
        x1 = wf - bx2; y1 = by1; x2 = wf - bx1; y2 = by2;   // undo hflip, same IEEE ops as ref
        sc = s2[m]; lb = l2[m];
    }
}

// ---------------- kernel 1: keys + global max coordinate ----------------
extern "C" __global__ __launch_bounds__(512)
void k_build(const float* __restrict__ b1, const float* __restrict__ b2,
             const float* __restrict__ s1, const float* __restrict__ s2,
             const int* __restrict__ l1, const int* __restrict__ l2,
             const int* __restrict__ widthp, char* __restrict__ ws)
{
#pragma clang fp contract(off)
    const int e = blockIdx.x * 512 + threadIdx.x;
    const float wf = get_width(widthp);
    float x1, y1, x2, y2, sc; int lb;
    fetch_cand(e, b1, b2, s1, s2, l1, l2, wf, x1, y1, x2, y2, sc, lb);

    float lmax = fmaxf(fmaxf(x1, y1), fmaxf(x2, y2));   // coords >= 0 (clipped)
    for (int d = 32; d > 0; d >>= 1) lmax = fmaxf(lmax, __shfl_xor(lmax, d));
    if ((threadIdx.x & 63) == 0)
        atomicMax(((int*)(ws + OFF_HDR)) + 1, __float_as_int(lmax));  // poison < 0, safe

    bool valid = sc >= SCORE_T;
    float s = valid ? sc : -1.0f;
    u64 key = ((u64)order_key(-s) << 32) | (unsigned)e;  // low bits = idx -> stable argsort
    ((u64*)(ws + OFF_KEYS))[e] = key;
}

// ---------------- kernel 2: counting sort, partial ranks ----------------
extern "C" __global__ __launch_bounds__(256)
void k_count(char* __restrict__ ws)
{
    __shared__ u64 tile[1024];
    const u64* keys = (const u64*)(ws + OFF_KEYS);
    const int i = blockIdx.x * 256 + threadIdx.x;
    const u64 mykey = keys[i];
    const int j0 = blockIdx.y * (M2 / JSPLIT);
    for (int q = threadIdx.x; q < M2 / JSPLIT; q += 256) tile[q] = keys[j0 + q];
    __syncthreads();
    int cnt = 0;
#pragma unroll 8
    for (int q = 0; q < M2 / JSPLIT; ++q) cnt += (tile[q] < mykey) ? 1 : 0;
    ((int*)(ws + OFF_PART))[blockIdx.y * M2 + i] = cnt;
}

// ---------------- kernel 3: combine ranks + scatter + V ----------------
extern "C" __global__ __launch_bounds__(1024)
void k_scatter(const float* __restrict__ b1, const float* __restrict__ b2,
               const float* __restrict__ s1, const float* __restrict__ s2,
               const int* __restrict__ l1, const int* __restrict__ l2,
               const int* __restrict__ widthp, char* __restrict__ ws)
{
#pragma clang fp contract(off)
    const int i = blockIdx.x * 1024 + threadIdx.x;
    const int* part = (const int*)(ws + OFF_PART);
    int rank = 0;
#pragma unroll
    for (int sp = 0; sp < JSPLIT; ++sp) rank += part[sp * M2 + i];

    const float wf = get_width(widthp);
    const float maxc = __int_as_float(((const int*)(ws + OFF_HDR))[1]) + 1.0f; // jnp.max(boxes)+1.0
    float x1, y1, x2, y2, sc; int lb;
    fetch_cand(i, b1, b2, s1, s2, l1, l2, wf, x1, y1, x2, y2, sc, lb);

    float off = (float)lb * maxc;               // one product then 4 adds, like ref
    float ox1 = x1 + off, oy1 = y1 + off, ox2 = x2 + off, oy2 = y2 + off;
    float area = (ox2 - ox1) * (oy2 - oy1);     // area of OFFSET boxes, like ref

    ((float4*)(ws + OFF_SB))[rank]   = make_float4(x1, y1, x2, y2);
    ((float4*)(ws + OFF_OBOX))[rank] = make_float4(ox1, oy1, ox2, oy2);
    ((float*)(ws + OFF_OAREA))[rank]  = area;
    ((float*)(ws + OFF_SSCORE))[rank] = sc;
    ((int*)(ws + OFF_SLABEL))[rank]   = lb;

    // valid entries (score>=T) sort strictly before invalid (-1): V = max valid rank + 1
    bool valid = sc >= SCORE_T;
    u64 bal = __ballot(valid);
    int vmax = valid ? rank + 1 : INT32_MIN;
    for (int d = 32; d > 0; d >>= 1) vmax = max(vmax, __shfl_xor(vmax, d));
    if ((threadIdx.x & 63) == 0 && bal)
        atomicMax((int*)(ws + OFF_HDR), vmax);  // poison < 0, safe
}

// ---------------- kernel 4: lower-triangle conflict bitmask (TRANSPOSED store) ----------------
// grid (128,128), one wave/block; mask_T[w][row] bit j = (iou(row, w*64+j) > T) && (w*64+j < row)
extern "C" __global__ __launch_bounds__(64)
void k_mask(char* __restrict__ ws)
{
#pragma clang fp contract(off)
    const int x = blockIdx.x;                   // row chunk
    const int y = blockIdx.y;                   // col word
    if (y > x) return;                          // strictly-upper words never read
    const int V = ((const int*)(ws + OFF_HDR))[0];
    if (x * 64 >= V) return;                    // rows >= V never scanned

    const float4* obox  = (const float4*)(ws + OFF_OBOX);
    const float*  oarea = (const float*) (ws + OFF_OAREA);
    u64* maskT = (u64*)(ws + OFF_MASK);

    const int lane = threadIdx.x;
    const int col  = y * 64 + lane;
    const float4 cb = obox[col];
    const float  ca = oarea[col];

    for (int r = 0; r < 64; ++r) {
        int row = x * 64 + r;
        float4 rb = obox[row];                  // wave-uniform -> broadcast
        float  ra = oarea[row];
        float ltx = fmaxf(rb.x, cb.x);
        float lty = fmaxf(rb.y, cb.y);
        float rbx = fminf(rb.z, cb.z);
        float rby = fminf(rb.w, cb.w);
        float wx = fmaxf(rbx - ltx, 0.0f);      // jnp.clip(rb-lt, 0)
        float wy = fmaxf(rby - lty, 0.0f);
        float inter = wx * wy;
        float denom = ((ra + ca) - inter) + 1e-9f;  // ref association order
        float iou = inter / denom;
        u64 m = __ballot((col < row) && (iou > IOU_T));
        if (lane == 0) maskT[(size_t)y * M2 + row] = m;
    }
}

// ---------------- kernel 5: chained exact NMS (single launch) ----------------
// Wave g of block b owns keep-word W = 4b+g (rows W*64..W*64+63, lane = row).
// Gauss-Seidel over words: word W resolves exactly once words 0..W-1 are final.
// In-word 64x64 recurrence: ballot fixpoint -> unique triangular fixed point (== greedy).
extern "C" __global__ __launch_bounds__(256)
void k_nms(char* __restrict__ ws)
{
    const int g = threadIdx.x >> 6, lane = threadIdx.x & 63;
    const int W = blockIdx.x * 4 + g;
    const int R = W * 64 + lane;
    const int V = ((const int*)(ws + OFF_HDR))[0];
    const int nw = (V > 0) ? ((V + 63) >> 6) : 0;
    u64* gkeep = (u64*)(ws + OFF_KEEP);
    int* progress = ((int*)(ws + OFF_HDR)) + 2;
    const u64* maskT = (const u64*)(ws + OFF_MASK);

    if (W >= nw) {                              // fully-invalid word: keep = 0, no chaining
        if (lane == 0) gkeep[W] = 0;
        return;
    }

    const u64 diag = maskT[(size_t)W * M2 + R]; // in-word lower-triangle conflicts of my row
    const bool v = (R < V);                     // valid entries occupy sorted ranks [0, V)

    u64 acc = 0;                                // OR of mask_T[w][R] & keep[w], w < W
    int done = 0;
    while (done < W) {
        int p = __hip_atomic_load(progress, __ATOMIC_ACQUIRE, __HIP_MEMORY_SCOPE_AGENT);
        p = __builtin_amdgcn_readfirstlane(p);
        if (p > W) p = W;
        while (done < p) {
            u64 kw = __hip_atomic_load(&gkeep[done], __ATOMIC_RELAXED, __HIP_MEMORY_SCOPE_AGENT);
            u64 m  = maskT[(size_t)done * M2 + R];   // 64 consecutive u64 across the wave
            acc |= m & kw;
            ++done;
        }
        if (done < W) __builtin_amdgcn_s_sleep(1);
    }

    const bool live = v && (acc == 0);          // not suppressed by any earlier kept word
    u64 k = __ballot(live);                     // k0 = f(0)
    for (int it = 0; it < 64; ++it) {           // terminates in <= chain depth; cap for safety
        bool killed = (diag & k) != 0;
        u64 k2 = __ballot(live && !killed);
        if (k2 == k) break;
        k = k2;
    }

    if (lane == 0) {
        __hip_atomic_store(&gkeep[W], k, __ATOMIC_RELAXED, __HIP_MEMORY_SCOPE_AGENT);
        // absolute W+1 (not increment): overwrites 0xAA poison without an init kernel
        __hip_atomic_store(progress, W + 1, __ATOMIC_RELEASE, __HIP_MEMORY_SCOPE_AGENT);
    }
}

// ---------------- kernel 6: masked outputs ----------------
// d_out (f32): boxes[8192*4] | labels[8192] | scores[8192] | keeps[8192]
extern "C" __global__ __launch_bounds__(256)
void k_out(const char* __restrict__ ws, float* __restrict__ out)
{
    const int p = blockIdx.x * 256 + threadIdx.x;
    const u64* keep = (const u64*)(ws + OFF_KEEP);
    int kb = (int)((keep[p >> 6] >> (p & 63)) & 1ull);

    float4 bx = ((const float4*)(ws + OFF_SB))[p];
    if (!kb) bx = make_float4(0.f, 0.f, 0.f, 0.f);
    ((float4*)out)[p] = bx;
    out[M2*4 + p] = kb ? (float)((const int*)(ws + OFF_SLABEL))[p] : -1.0f;
    out[M2*5 + p] = kb ? ((const float*)(ws + OFF_SSCORE))[p] : 0.0f;
    out[M2*6 + p] = kb ? 1.0f : 0.0f;
}

extern "C" void kernel_launch(void* const* d_in, const int* in_sizes, int n_in,
                              void* d_out, int out_size, void* d_ws, size_t ws_size,
                              hipStream_t stream)
{
    const float* boxes1  = (const float*)d_in[0];
    const float* boxes2  = (const float*)d_in[1];
    const float* scores1 = (const float*)d_in[2];
    const float* scores2 = (const float*)d_in[3];
    const int*   labels1 = (const int*)d_in[4];
    const int*   labels2 = (const int*)d_in[5];
    const int*   widthp  = (const int*)d_in[6];
    char* ws = (char*)d_ws;

    hipLaunchKernelGGL(k_build, dim3(M2 / 512), dim3(512), 0, stream,
                       boxes1, boxes2, scores1, scores2, labels1, labels2, widthp, ws);
    hipLaunchKernelGGL(k_count, dim3(M2 / 256, JSPLIT), dim3(256), 0, stream, ws);
    hipLaunchKernelGGL(k_scatter, dim3(M2 / 1024), dim3(1024), 0, stream,
                       boxes1, boxes2, scores1, scores2, labels1, labels2, widthp, ws);
    hipLaunchKernelGGL(k_mask, dim3(NWORDS, NWORDS), dim3(64), 0, stream, ws);
    hipLaunchKernelGGL(k_nms, dim3(NWORDS / 4), dim3(256), 0, stream, ws);
    hipLaunchKernelGGL(k_out, dim3(M2 / 256), dim3(256), 0, stream, ws, (float*)d_out);
}

// Round 4
// 175.226 us; speedup vs baseline: 1.3310x; 1.3310x over previous
//
#include <hip/hip_runtime.h>
#include <stdint.h>

typedef unsigned long long u64;

#define NCAND   4096
#define M2      8192            // 2N
#define NWORDS  128             // M2/64
#define SCORE_T 0.5f
#define IOU_T   0.5f
#define JSPLIT  16              // j-range splits for the counting sort

// ---------------- workspace layout (bytes) ----------------
// hdr[0] = V (atomicMax in k_scatter; 0xAA poison is negative -> no init needed)
// hdr[1] = maxcoord f32 bits (atomicMax in k_build; poison negative -> safe)
#define OFF_HDR     0
#define OFF_KEYS    4096                       // u64[8192]
#define OFF_PART    (OFF_KEYS + 65536)         // int[JSPLIT][8192]
#define OFF_OAREA   (OFF_PART + JSPLIT*32768)  // float[8192]
#define OFF_SSCORE  (OFF_OAREA + 32768)        // float[8192] sorted original scores
#define OFF_SLABEL  (OFF_SSCORE + 32768)       // int[8192]   sorted labels
#define OFF_SB      (OFF_SLABEL + 32768)       // float4[8192] sorted boxes
#define OFF_OBOX    (OFF_SB + 131072)          // float4[8192] sorted offset boxes
#define OFF_MASK    (OFF_OBOX + 131072)        // u64 mask_T[128][8192]  (TRANSPOSED: word-major)
// total ≈ 9.4 MiB

__device__ __forceinline__ unsigned order_key(float f) {
    unsigned u = __float_as_uint(f);
    return (u & 0x80000000u) ? ~u : (u | 0x80000000u);  // ascending uint == ascending float
}

__device__ __forceinline__ float get_width(const int* widthp) {
    int wi = widthp[0];
    return (wi > 0 && wi < 1000000) ? (float)wi : __int_as_float(wi);
}

// Recompute the combined (flip-adjusted) candidate `idx` straight from inputs.
__device__ __forceinline__ void fetch_cand(int idx, const float* b1, const float* b2,
                                           const float* s1, const float* s2,
                                           const int* l1, const int* l2, float wf,
                                           float& x1, float& y1, float& x2, float& y2,
                                           float& sc, int& lb) {
#pragma clang fp contract(off)
    if (idx < NCAND) {
        x1 = b1[idx*4+0]; y1 = b1[idx*4+1]; x2 = b1[idx*4+2]; y2 = b1[idx*4+3];
        sc = s1[idx]; lb = l1[idx];
    } else {
        int m = idx - NCAND;
        float bx1 = b2[m*4+0], by1 = b2[m*4+1], bx2 = b2[m*4+2], by2 = b2[m*4+3];
        x1 = wf - bx2; y1 = by1; x2 = wf - bx1; y2 = by2;   // undo hflip, same IEEE ops as ref
        sc = s2[m]; lb = l2[m];
    }
}

// ---------------- kernel 1: keys + global max coordinate ----------------
extern "C" __global__ __launch_bounds__(512)
void k_build(const float* __restrict__ b1, const float* __restrict__ b2,
             const float* __restrict__ s1, const float* __restrict__ s2,
             const int* __restrict__ l1, const int* __restrict__ l2,
             const int* __restrict__ widthp, char* __restrict__ ws)
{
#pragma clang fp contract(off)
    const int e = blockIdx.x * 512 + threadIdx.x;
    const float wf = get_width(widthp);
    float x1, y1, x2, y2, sc; int lb;
    fetch_cand(e, b1, b2, s1, s2, l1, l2, wf, x1, y1, x2, y2, sc, lb);

    float lmax = fmaxf(fmaxf(x1, y1), fmaxf(x2, y2));   // coords >= 0 (clipped)
    for (int d = 32; d > 0; d >>= 1) lmax = fmaxf(lmax, __shfl_xor(lmax, d));
    if ((threadIdx.x & 63) == 0)
        atomicMax(((int*)(ws + OFF_HDR)) + 1, __float_as_int(lmax));  // poison < 0, safe

    bool valid = sc >= SCORE_T;
    float s = valid ? sc : -1.0f;
    u64 key = ((u64)order_key(-s) << 32) | (unsigned)e;  // low bits = idx -> stable argsort
    ((u64*)(ws + OFF_KEYS))[e] = key;
}

// ---------------- kernel 2: counting sort, partial ranks ----------------
extern "C" __global__ __launch_bounds__(256)
void k_count(char* __restrict__ ws)
{
    __shared__ u64 tile[M2 / JSPLIT];
    const u64* keys = (const u64*)(ws + OFF_KEYS);
    const int i = blockIdx.x * 256 + threadIdx.x;
    const u64 mykey = keys[i];
    const int j0 = blockIdx.y * (M2 / JSPLIT);
    for (int q = threadIdx.x; q < M2 / JSPLIT; q += 256) tile[q] = keys[j0 + q];
    __syncthreads();
    int cnt = 0;
#pragma unroll 8
    for (int q = 0; q < M2 / JSPLIT; ++q) cnt += (tile[q] < mykey) ? 1 : 0;
    ((int*)(ws + OFF_PART))[blockIdx.y * M2 + i] = cnt;
}

// ---------------- kernel 3: combine ranks + scatter + V ----------------
extern "C" __global__ __launch_bounds__(1024)
void k_scatter(const float* __restrict__ b1, const float* __restrict__ b2,
               const float* __restrict__ s1, const float* __restrict__ s2,
               const int* __restrict__ l1, const int* __restrict__ l2,
               const int* __restrict__ widthp, char* __restrict__ ws)
{
#pragma clang fp contract(off)
    const int i = blockIdx.x * 1024 + threadIdx.x;
    const int* part = (const int*)(ws + OFF_PART);
    int rank = 0;
#pragma unroll
    for (int sp = 0; sp < JSPLIT; ++sp) rank += part[sp * M2 + i];

    const float wf = get_width(widthp);
    const float maxc = __int_as_float(((const int*)(ws + OFF_HDR))[1]) + 1.0f; // jnp.max(boxes)+1.0
    float x1, y1, x2, y2, sc; int lb;
    fetch_cand(i, b1, b2, s1, s2, l1, l2, wf, x1, y1, x2, y2, sc, lb);

    float off = (float)lb * maxc;               // one product then 4 adds, like ref
    float ox1 = x1 + off, oy1 = y1 + off, ox2 = x2 + off, oy2 = y2 + off;
    float area = (ox2 - ox1) * (oy2 - oy1);     // area of OFFSET boxes, like ref

    ((float4*)(ws + OFF_SB))[rank]   = make_float4(x1, y1, x2, y2);
    ((float4*)(ws + OFF_OBOX))[rank] = make_float4(ox1, oy1, ox2, oy2);
    ((float*)(ws + OFF_OAREA))[rank]  = area;
    ((float*)(ws + OFF_SSCORE))[rank] = sc;
    ((int*)(ws + OFF_SLABEL))[rank]   = lb;

    // valid entries (score>=T) sort strictly before invalid (-1): V = max valid rank + 1
    bool valid = sc >= SCORE_T;
    u64 bal = __ballot(valid);
    int vmax = valid ? rank + 1 : INT32_MIN;
    for (int d = 32; d > 0; d >>= 1) vmax = max(vmax, __shfl_xor(vmax, d));
    if ((threadIdx.x & 63) == 0 && bal)
        atomicMax((int*)(ws + OFF_HDR), vmax);  // poison < 0, safe
}

// ---------------- kernel 4: lower-triangle conflict bitmask (TRANSPOSED store) ----------------
// grid (128,128), one wave/block; mask_T[w][row] bit j = (iou(row, w*64+j) > T) && (w*64+j < row)
extern "C" __global__ __launch_bounds__(64)
void k_mask(char* __restrict__ ws)
{
#pragma clang fp contract(off)
    const int x = blockIdx.x;                   // row chunk
    const int y = blockIdx.y;                   // col word
    if (y > x) return;                          // strictly-upper words never read
    const int V = ((const int*)(ws + OFF_HDR))[0];
    if (x * 64 >= V) return;                    // rows >= V never scanned

    const float4* obox  = (const float4*)(ws + OFF_OBOX);
    const float*  oarea = (const float*) (ws + OFF_OAREA);
    u64* maskT = (u64*)(ws + OFF_MASK);

    const int lane = threadIdx.x;
    const int col  = y * 64 + lane;
    const float4 cb = obox[col];
    const float  ca = oarea[col];

    for (int r = 0; r < 64; ++r) {
        int row = x * 64 + r;
        float4 rb = obox[row];                  // wave-uniform -> broadcast
        float  ra = oarea[row];
        float ltx = fmaxf(rb.x, cb.x);
        float lty = fmaxf(rb.y, cb.y);
        float rbx = fminf(rb.z, cb.z);
        float rby = fminf(rb.w, cb.w);
        float wx = fmaxf(rbx - ltx, 0.0f);      // jnp.clip(rb-lt, 0)
        float wy = fmaxf(rby - lty, 0.0f);
        float inter = wx * wy;
        float denom = ((ra + ca) - inter) + 1e-9f;  // ref association order
        float iou = inter / denom;
        u64 m = __ballot((col < row) && (iou > IOU_T));
        if (lane == 0) maskT[(size_t)y * M2 + row] = m;
    }
}

// ---------------- kernel 5: single-block LDS-chained exact NMS + fused output ----------------
// 16 waves; wave g owns words g, g+16, ... in global chain order. Chain hops go through
// LDS (workgroup-scope release/acquire == lgkmcnt wait, ~10s of cycles, vs ~1.7us cross-CU).
// Mask rows are prefetched while waiting (they don't depend on keep), so each hop's
// critical path is poll + AND + ballot fixpoint + publish.
extern "C" __global__ __launch_bounds__(1024)
void k_nms_out(char* __restrict__ ws, float* __restrict__ out)
{
    __shared__ u64 keep_lds[NWORDS];
    __shared__ int s_prog;
    const int tid = threadIdx.x;
    const int g = tid >> 6, lane = tid & 63;
    const int V = ((const int*)(ws + OFF_HDR))[0];
    const int nw = (V > 0) ? ((V + 63) >> 6) : 0;   // words participating in the chain
    const u64* maskT = (const u64*)(ws + OFF_MASK);

    if (tid == 0) s_prog = 0;
    __syncthreads();

    for (int W = g; W < NWORDS; W += 16) {
        if (W >= nw) {                          // fully-invalid word: keep = 0, no chain
            if (lane == 0)
                __hip_atomic_store(&keep_lds[W], (u64)0, __ATOMIC_RELAXED, __HIP_MEMORY_SCOPE_WORKGROUP);
            continue;
        }
        const int R = W * 64 + lane;
        const u64 diag = maskT[(size_t)W * M2 + R];  // in-word lower-triangle conflicts
        u64 acc = 0;
        if (W > 0) {
            int done = 0;
            u64 mpref = maskT[(size_t)0 * M2 + R];   // prefetch: mask is keep-independent
            int guard = 0;
            while (done < W && guard < (1 << 18)) {
                int p = __hip_atomic_load(&s_prog, __ATOMIC_ACQUIRE, __HIP_MEMORY_SCOPE_WORKGROUP);
                if (p <= done) { __builtin_amdgcn_s_sleep(1); ++guard; continue; }
                if (p > W) p = W;
                while (done < p) {
                    u64 kw = __hip_atomic_load(&keep_lds[done], __ATOMIC_RELAXED, __HIP_MEMORY_SCOPE_WORKGROUP);
                    acc |= mpref & kw;
                    ++done;
                    if (done < W) mpref = maskT[(size_t)done * M2 + R];
                }
            }
        }
        const bool live = (R < V) && (acc == 0);     // not suppressed by earlier kept words
        u64 k = __ballot(live);
        for (int it = 0; it < 64; ++it) {            // unique triangular fixed point == greedy
            bool killed = (diag & k) != 0;
            u64 k2 = __ballot(live && !killed);
            if (k2 == k) break;
            k = k2;
        }
        if (lane == 0) {
            __hip_atomic_store(&keep_lds[W], k, __ATOMIC_RELAXED, __HIP_MEMORY_SCOPE_WORKGROUP);
            __hip_atomic_store(&s_prog, W + 1, __ATOMIC_RELEASE, __HIP_MEMORY_SCOPE_WORKGROUP);
        }
    }
    __syncthreads();

    // fused masked outputs: d_out (f32) = boxes[8192*4] | labels[8192] | scores[8192] | keeps[8192]
    for (int i = 0; i < M2 / 1024; ++i) {
        int p = tid + i * 1024;
        int kb = (int)((keep_lds[p >> 6] >> (p & 63)) & 1ull);
        float4 bx = ((const float4*)(ws + OFF_SB))[p];
        if (!kb) bx = make_float4(0.f, 0.f, 0.f, 0.f);
        ((float4*)out)[p] = bx;
        out[M2*4 + p] = kb ? (float)((const int*)(ws + OFF_SLABEL))[p] : -1.0f;
        out[M2*5 + p] = kb ? ((const float*)(ws + OFF_SSCORE))[p] : 0.0f;
        out[M2*6 + p] = kb ? 1.0f : 0.0f;
    }
}

extern "C" void kernel_launch(void* const* d_in, const int* in_sizes, int n_in,
                              void* d_out, int out_size, void* d_ws, size_t ws_size,
                              hipStream_t stream)
{
    const float* boxes1  = (const float*)d_in[0];
    const float* boxes2  = (const float*)d_in[1];
    const float* scores1 = (const float*)d_in[2];
    const float* scores2 = (const float*)d_in[3];
    const int*   labels1 = (const int*)d_in[4];
    const int*   labels2 = (const int*)d_in[5];
    const int*   widthp  = (const int*)d_in[6];
    char* ws = (char*)d_ws;

    hipLaunchKernelGGL(k_build, dim3(M2 / 512), dim3(512), 0, stream,
                       boxes1, boxes2, scores1, scores2, labels1, labels2, widthp, ws);
    hipLaunchKernelGGL(k_count, dim3(M2 / 256, JSPLIT), dim3(256), 0, stream, ws);
    hipLaunchKernelGGL(k_scatter, dim3(M2 / 1024), dim3(1024), 0, stream,
                       boxes1, boxes2, scores1, scores2, labels1, labels2, widthp, ws);
    hipLaunchKernelGGL(k_mask, dim3(NWORDS, NWORDS), dim3(64), 0, stream, ws);
    hipLaunchKernelGGL(k_nms_out, dim3(1), dim3(1024), 0, stream, ws, (float*)d_out);
}